// Round 1
// baseline (5958.445 us; speedup 1.0000x reference)
//
#include <hip/hip_runtime.h>
#include <math.h>

#define DD 1024
#define NN 4096
#define MM 4096
#define CC 16

// ---------------- workspace layout (float offsets) ----------------
#define OFF_XG     ((size_t)0)          // 4096*1024
#define OFF_BASE   ((size_t)4194304)    // 1024*1024
#define OFF_L      ((size_t)5242880)    // 1024*1024
#define OFF_SIGMA  ((size_t)6291456)    // 16*1024*1024
#define OFF_DINV   ((size_t)23068672)   // 16*16*64*64
#define OFF_SUMS   ((size_t)24117248)   // 16*1024
#define OFF_MU     ((size_t)24133632)   // 16*1024
#define OFF_U      ((size_t)24150016)   // 16*1024
#define OFF_MU2    ((size_t)24166400)   // 16
#define OFF_XQ2    ((size_t)24166416)   // 4096
#define OFF_XQMU   ((size_t)24170512)   // 4096*16
#define OFF_KAPNU  ((size_t)24236048)   // 2
#define OFF_CF     ((size_t)24236056)   // 16
#define OFF_BETA   ((size_t)24236072)   // 16
#define OFF_INVS   ((size_t)24236088)   // 16
#define OFF_INTS   ((size_t)24236104)   // ints: counts16, offsets16, cursor16, order4096

__device__ __forceinline__ void tri_decode(int b, int& ti, int& tj) {
  int t = 0;
  while ((t + 1) * (t + 2) / 2 <= b) t++;
  ti = t;
  tj = b - t * (t + 1) / 2;
}

__device__ __forceinline__ float reduce256(float v, float* scratch) {
  for (int o = 32; o > 0; o >>= 1) v += __shfl_down(v, o, 64);
  int lane = threadIdx.x & 63, w = threadIdx.x >> 6;
  __syncthreads();
  if (lane == 0) scratch[w] = v;
  __syncthreads();
  return scratch[0] + scratch[1] + scratch[2] + scratch[3];
}

// ---------------- stats ----------------
__global__ void k_scalars(const int* y, const float* kappa, const float* nu,
                          float* kapnu, float* cf, float* beta, float* invs,
                          int* counts, int* offsets, int* cursor, float* sums,
                          float* dout) {
  __shared__ int h[CC];
  int t = threadIdx.x;
  if (t < CC) h[t] = 0;
  __syncthreads();
  for (int n = t; n < NN; n += 256) atomicAdd(&h[y[n]], 1);
  __syncthreads();
  if (t == 0) {
    float kap = fabsf(kappa[0]) + 1e-6f;
    float nu_ = fmaxf(nu[0], (float)DD - 1.0f + 1e-6f);
    kapnu[0] = kap; kapnu[1] = nu_;
    int off = 0;
    for (int c = 0; c < CC; c++) {
      counts[c] = h[c]; offsets[c] = off; cursor[c] = off; off += h[c];
      cf[c] = (float)h[c];
      beta[c] = kap + (float)h[c];
      invs[c] = 1.0f / (nu_ + (float)h[c] + (float)DD + 2.0f);
    }
  }
  for (size_t i = t; i < (size_t)CC * DD; i += 256) sums[i] = 0.f;
  for (size_t i = t; i < (size_t)MM * CC; i += 256) dout[i] = 0.f;
}

__global__ void k_colsums(const float* X, const int* y, float* sums) {
  __shared__ float acc[CC][256];
  int t = threadIdx.x;
  int col = blockIdx.x * 256 + t;
  for (int c = 0; c < CC; c++) acc[c][t] = 0.f;
  int r0 = blockIdx.y * 512;
  for (int r = r0; r < r0 + 512; r++) {
    int c = y[r];
    acc[c][t] += X[(size_t)r * DD + col];
  }
  for (int c = 0; c < CC; c++) atomicAdd(&sums[(size_t)c * DD + col], acc[c][t]);
}

__global__ void k_mu(const float* sums, const float* m, const float* kapnu,
                     const float* cf, float* mu) {
  int i = blockIdx.x * 256 + threadIdx.x;
  int c = i >> 10, j = i & 1023;
  float kap = kapnu[0];
  mu[i] = (kap * m[j] + sums[i]) / (kap + cf[c]);
}

__global__ void k_mu2(const float* mu, float* mu2) {
  __shared__ float scratch[4];
  int cls = blockIdx.x, t = threadIdx.x;
  float s = 0.f;
  for (int j = t; j < DD; j += 256) {
    float v = mu[(size_t)cls * DD + j];
    s += v * v;
  }
  float tot = reduce256(s, scratch);
  if (t == 0) mu2[cls] = tot;
}

__global__ void k_scatter(const int* y, int* cursor, int* order) {
  int n = blockIdx.x * 256 + threadIdx.x;
  int c = y[n];
  int p = atomicAdd(&cursor[c], 1);
  order[p] = n;
}

__global__ void k_gather(const float* X, const int* order, float* Xg) {
  int p = blockIdx.x;
  int src = order[p];
  for (int j = threadIdx.x; j < DD; j += 256)
    Xg[(size_t)p * DD + j] = X[(size_t)src * DD + j];
}

__global__ void k_buildL(const float* td, const float* tl, float* L) {
  size_t idx = (size_t)blockIdx.x * 256 + threadIdx.x;
  int i = (int)(idx >> 10), j = (int)(idx & 1023);
  float v;
  if (i == j) v = fabsf(td[i]);
  else if (i > j) v = tl[idx];
  else v = 0.f;
  L[idx] = v;
}

// base = L*L^T + kap*m*m^T  (lower tiles only, diag tiles full)
__global__ void k_base(const float* L, const float* m, const float* kapnu, float* base) {
  int ti, tj; tri_decode(blockIdx.x, ti, tj);
  __shared__ float Ta[16][65], Tb[16][65];
  int t = threadIdx.x, tx = t & 15, ty = t >> 4;
  int r0 = ty * 4, c0 = tx * 4;
  float acc[4][4] = {};
  int kmax = (tj + 1) * 64;
  for (int kk = 0; kk < kmax; kk += 16) {
    __syncthreads();
    for (int idx = t; idx < 64 * 16; idx += 256) {
      int r = idx >> 4, p = idx & 15;
      Ta[p][r] = L[(size_t)(ti * 64 + r) * DD + kk + p];
      Tb[p][r] = L[(size_t)(tj * 64 + r) * DD + kk + p];
    }
    __syncthreads();
#pragma unroll
    for (int p = 0; p < 16; p++) {
      float av[4], bv[4];
#pragma unroll
      for (int a = 0; a < 4; a++) av[a] = Ta[p][r0 + a];
#pragma unroll
      for (int b = 0; b < 4; b++) bv[b] = Tb[p][c0 + b];
#pragma unroll
      for (int a = 0; a < 4; a++)
#pragma unroll
        for (int b = 0; b < 4; b++) acc[a][b] += av[a] * bv[b];
    }
  }
  float kap = kapnu[0];
#pragma unroll
  for (int a = 0; a < 4; a++)
#pragma unroll
    for (int b = 0; b < 4; b++) {
      int gi = ti * 64 + r0 + a, gj = tj * 64 + c0 + b;
      base[(size_t)gi * DD + gj] = acc[a][b] + kap * m[gi] * m[gj];
    }
}

// sigma_c = (base + X_c^T X_c - beta*mu*mu^T) * invs   (lower tiles, diag full)
__global__ void k_syrk_sigma(const float* Xg, const float* base, const float* mu,
                             const float* beta, const float* invs,
                             const int* counts, const int* offsets, float* sigma) {
  int b = blockIdx.x;
  int cls = b / 136, tr = b % 136;
  int ti, tj; tri_decode(tr, ti, tj);
  int cnt = counts[cls], off = offsets[cls];
  float* Sg = sigma + (size_t)cls * DD * DD;
  const float* muc = mu + (size_t)cls * DD;
  __shared__ float Xa[16][65], Xb[16][65];
  int t = threadIdx.x, tx = t & 15, ty = t >> 4;
  int r0 = ty * 4, c0 = tx * 4;
  float acc[4][4] = {};
  for (int kk = 0; kk < cnt; kk += 16) {
    __syncthreads();
    for (int idx = t; idx < 16 * 64; idx += 256) {
      int p = idx >> 6, rc = idx & 63;
      int row = kk + p;
      float va = 0.f, vb = 0.f;
      if (row < cnt) {
        va = Xg[(size_t)(off + row) * DD + ti * 64 + rc];
        vb = Xg[(size_t)(off + row) * DD + tj * 64 + rc];
      }
      Xa[p][rc] = va; Xb[p][rc] = vb;
    }
    __syncthreads();
#pragma unroll
    for (int p = 0; p < 16; p++) {
      float av[4], bv[4];
#pragma unroll
      for (int a = 0; a < 4; a++) av[a] = Xa[p][r0 + a];
#pragma unroll
      for (int b2 = 0; b2 < 4; b2++) bv[b2] = Xb[p][c0 + b2];
#pragma unroll
      for (int a = 0; a < 4; a++)
#pragma unroll
        for (int b2 = 0; b2 < 4; b2++) acc[a][b2] += av[a] * bv[b2];
    }
  }
  float bet = beta[cls], isc = invs[cls];
#pragma unroll
  for (int a = 0; a < 4; a++)
#pragma unroll
    for (int b2 = 0; b2 < 4; b2++) {
      int gi = ti * 64 + r0 + a, gj = tj * 64 + c0 + b2;
      float v = acc[a][b2] + base[(size_t)gi * DD + gj] - bet * muc[gi] * muc[gj];
      Sg[(size_t)gi * DD + gj] = v * isc;
    }
}

// ---------------- batched blocked Cholesky (NB=64) ----------------
__global__ void k_chol_diag(float* sigma, float* Dinv, int k) {
  int cls = blockIdx.x;
  float* Sg = sigma + (size_t)cls * DD * DD;
  __shared__ float A[64][65];
  __shared__ float W[64][65];
  int t = threadIdx.x;
  for (int idx = t; idx < 4096; idx += 256) {
    int r = idx >> 6, c = idx & 63;
    A[r][c] = Sg[(size_t)(k * 64 + r) * DD + k * 64 + c];
    W[r][c] = 0.f;
  }
  __syncthreads();
  for (int j = 0; j < 64; j++) {
    if (t == 0) A[j][j] = sqrtf(A[j][j]);
    __syncthreads();
    float rpj = 1.0f / A[j][j];
    for (int r = j + 1 + t; r < 64; r += 256) A[r][j] *= rpj;
    __syncthreads();
    for (int idx = t; idx < 4096; idx += 256) {
      int r = idx >> 6, c = idx & 63;
      if (r > j && c > j) A[r][c] -= A[r][j] * A[c][j];
    }
    __syncthreads();
  }
  // W = inv(A_lower), one column per thread (t<64)
  if (t < 64) {
    int j = t;
    W[j][j] = 1.0f / A[j][j];
    for (int i = j + 1; i < 64; i++) {
      float s = 0.f;
      for (int kk = j; kk < i; kk++) s += A[i][kk] * W[kk][j];
      W[i][j] = -s / A[i][i];
    }
  }
  __syncthreads();
  for (int idx = t; idx < 4096; idx += 256) {
    int r = idx >> 6, c = idx & 63;
    Sg[(size_t)(k * 64 + r) * DD + k * 64 + c] = (c <= r) ? A[r][c] : 0.f;
    Dinv[((size_t)cls * 16 + k) * 4096 + idx] = W[r][c];
  }
}

__global__ void k_chol_panel(float* sigma, const float* Dinv, int k) {
  int nb = 15 - k;
  int cls = blockIdx.x / nb, sub = blockIdx.x % nb;
  int it = k + 1 + sub;
  float* Sg = sigma + (size_t)cls * DD * DD;
  __shared__ float At[64][65], Di[64][65];
  int t = threadIdx.x, tx = t & 15, ty = t >> 4;
  int r0 = ty * 4, c0 = tx * 4;
  for (int idx = t; idx < 4096; idx += 256) {
    int r = idx >> 6, p = idx & 63;
    At[r][p] = Sg[(size_t)(it * 64 + r) * DD + k * 64 + p];
    Di[r][p] = Dinv[((size_t)cls * 16 + k) * 4096 + idx];
  }
  __syncthreads();
  float acc[4][4] = {};
#pragma unroll 8
  for (int p = 0; p < 64; p++) {
    float av[4], bv[4];
#pragma unroll
    for (int a = 0; a < 4; a++) av[a] = At[r0 + a][p];
#pragma unroll
    for (int b = 0; b < 4; b++) bv[b] = Di[c0 + b][p];
#pragma unroll
    for (int a = 0; a < 4; a++)
#pragma unroll
      for (int b = 0; b < 4; b++) acc[a][b] += av[a] * bv[b];
  }
#pragma unroll
  for (int a = 0; a < 4; a++)
#pragma unroll
    for (int b = 0; b < 4; b++)
      Sg[(size_t)(it * 64 + r0 + a) * DD + k * 64 + c0 + b] = acc[a][b];
}

__global__ void k_chol_syrk(float* sigma, int k) {
  int nrem = 15 - k;
  int nt = nrem * (nrem + 1) / 2;
  int cls = blockIdx.x / nt, s = blockIdx.x % nt;
  int a_, b_; tri_decode(s, a_, b_);
  int it = k + 1 + a_, jt = k + 1 + b_;
  float* Sg = sigma + (size_t)cls * DD * DD;
  __shared__ float La[64][65], Lb[64][65];
  int t = threadIdx.x, tx = t & 15, ty = t >> 4;
  int r0 = ty * 4, c0 = tx * 4;
  for (int idx = t; idx < 4096; idx += 256) {
    int r = idx >> 6, p = idx & 63;
    La[r][p] = Sg[(size_t)(it * 64 + r) * DD + k * 64 + p];
    Lb[r][p] = Sg[(size_t)(jt * 64 + r) * DD + k * 64 + p];
  }
  __syncthreads();
  float acc[4][4] = {};
#pragma unroll 8
  for (int p = 0; p < 64; p++) {
    float av[4], bv[4];
#pragma unroll
    for (int a = 0; a < 4; a++) av[a] = La[r0 + a][p];
#pragma unroll
    for (int b = 0; b < 4; b++) bv[b] = Lb[c0 + b][p];
#pragma unroll
    for (int a = 0; a < 4; a++)
#pragma unroll
      for (int b = 0; b < 4; b++) acc[a][b] += av[a] * bv[b];
  }
#pragma unroll
  for (int a = 0; a < 4; a++)
#pragma unroll
    for (int b = 0; b < 4; b++) {
      size_t addr = (size_t)(it * 64 + r0 + a) * DD + jt * 64 + c0 + b;
      Sg[addr] -= acc[a][b];
    }
}

// ---------------- V = R^{-1}, stored transposed in upper triangle ----------------
__global__ void k_vlevel(float* sigma, const float* Dinv, int l) {
  int nb = 16 - l;
  int cls = blockIdx.x / nb, j = blockIdx.x % nb;
  int i = j + l;
  float* Sg = sigma + (size_t)cls * DD * DD;
  const float* Dv = Dinv + (size_t)cls * 16 * 4096;
  __shared__ float Ta[64][65], Tb[64][65], Ts[64][65];
  int t = threadIdx.x, tx = t & 15, ty = t >> 4;
  int r0 = ty * 4, c0 = tx * 4;
  float acc[4][4] = {};
  for (int k2 = j; k2 < i; k2++) {
    __syncthreads();
    for (int idx = t; idx < 4096; idx += 256) {
      int r = idx >> 6, p = idx & 63;
      Ta[r][p] = Sg[(size_t)(i * 64 + r) * DD + k2 * 64 + p];
    }
    if (k2 == j) {
      for (int idx = t; idx < 4096; idx += 256) {
        int p = idx >> 6, c = idx & 63;
        Tb[c][p] = Dv[(size_t)j * 4096 + idx];
      }
    } else {
      for (int idx = t; idx < 4096; idx += 256) {
        int c = idx >> 6, p = idx & 63;
        Tb[c][p] = Sg[(size_t)(j * 64 + c) * DD + k2 * 64 + p];
      }
    }
    __syncthreads();
#pragma unroll 8
    for (int p = 0; p < 64; p++) {
      float av[4], bv[4];
#pragma unroll
      for (int a = 0; a < 4; a++) av[a] = Ta[r0 + a][p];
#pragma unroll
      for (int b = 0; b < 4; b++) bv[b] = Tb[c0 + b][p];
#pragma unroll
      for (int a = 0; a < 4; a++)
#pragma unroll
        for (int b = 0; b < 4; b++) acc[a][b] += av[a] * bv[b];
    }
  }
  __syncthreads();
#pragma unroll
  for (int a = 0; a < 4; a++)
#pragma unroll
    for (int b = 0; b < 4; b++) Ts[r0 + a][c0 + b] = acc[a][b];
  for (int idx = t; idx < 4096; idx += 256) {
    int r = idx >> 6, p = idx & 63;
    Ta[r][p] = Dv[(size_t)i * 4096 + idx];
  }
  __syncthreads();
  float acc2[4][4] = {};
#pragma unroll 8
  for (int p = 0; p < 64; p++) {
    float av[4], bv[4];
#pragma unroll
    for (int a = 0; a < 4; a++) av[a] = Ta[r0 + a][p];
#pragma unroll
    for (int b = 0; b < 4; b++) bv[b] = Ts[p][c0 + b];
#pragma unroll
    for (int a = 0; a < 4; a++)
#pragma unroll
      for (int b = 0; b < 4; b++) acc2[a][b] += av[a] * bv[b];
  }
  __syncthreads();
#pragma unroll
  for (int a = 0; a < 4; a++)
#pragma unroll
    for (int b = 0; b < 4; b++) Ts[r0 + a][c0 + b] = -acc2[a][b];
  __syncthreads();
  for (int idx = t; idx < 4096; idx += 256) {
    int rr = idx & 63, cc = idx >> 6;
    Sg[(size_t)(j * 64 + cc) * DD + i * 64 + rr] = Ts[rr][cc];
  }
}

__global__ void k_finalizeV(float* sigma, const float* Dinv) {
  int cls = blockIdx.x >> 4, i = blockIdx.x & 15;
  float* Sg = sigma + (size_t)cls * DD * DD;
  const float* Dv = Dinv + ((size_t)cls * 16 + i) * 4096;
  for (int idx = threadIdx.x; idx < 4096; idx += 256) {
    int a = idx >> 6, b = idx & 63;
    Sg[(size_t)(i * 64 + a) * DD + i * 64 + b] = Dv[b * 64 + a];
  }
}

// u_c = V * mu_c  (via U = V^T stored in sigma)
__global__ void k_u(const float* sigma, const float* mu, float* u) {
  int cls = blockIdx.x >> 2, blk = blockIdx.x & 3;
  int i = blk * 256 + threadIdx.x;
  const float* Ug = sigma + (size_t)cls * DD * DD;
  const float* muc = mu + (size_t)cls * DD;
  float s = 0.f;
  for (int j = 0; j <= i; j++) s += Ug[(size_t)j * DD + i] * muc[j];
  u[(size_t)cls * DD + i] = s;
}

__global__ void k_xqdots(const float* Xq, const float* mu, float* xq2, float* xqmu) {
  __shared__ float xrow[DD];
  __shared__ float scratch[4];
  int m = blockIdx.x, t = threadIdx.x;
  for (int j = t; j < DD; j += 256) xrow[j] = Xq[(size_t)m * DD + j];
  __syncthreads();
  float s2 = 0.f;
  for (int j = t; j < DD; j += 256) s2 += xrow[j] * xrow[j];
  float tot = reduce256(s2, scratch);
  if (t == 0) xq2[m] = tot;
  for (int c = 0; c < CC; c++) {
    float s = 0.f;
    for (int j = t; j < DD; j += 256) s += xrow[j] * mu[(size_t)c * DD + j];
    tot = reduce256(s, scratch);
    if (t == 0) xqmu[(size_t)m * CC + c] = tot;
  }
}

// fused G = Xq*U (K bound (it+1)*64), epilogue: atomicAdd row partial of ||G-u||^2
__global__ void k_gemmG_fused(const float* Xq, const float* sigma, const float* u,
                              float* dout) {
  int mt = blockIdx.x, it = blockIdx.y, cls = blockIdx.z;
  const float* Ug = sigma + (size_t)cls * DD * DD;
  const float* uc = u + (size_t)cls * DD;
  __shared__ float As[64][17];
  __shared__ float Bs[16][65];
  int t = threadIdx.x, tx = t & 15, ty = t >> 4;
  int m0 = mt * 64, i0 = it * 64;
  int r0 = ty * 4, c0 = tx * 4;
  float acc[4][4] = {};
  int kmax = (it + 1) * 64;
  for (int kk = 0; kk < kmax; kk += 16) {
    __syncthreads();
    for (int idx = t; idx < 64 * 16; idx += 256) {
      int r = idx >> 4, p = idx & 15;
      As[r][p] = Xq[(size_t)(m0 + r) * DD + kk + p];
    }
    for (int idx = t; idx < 16 * 64; idx += 256) {
      int p = idx >> 6, c = idx & 63;
      Bs[p][c] = Ug[(size_t)(kk + p) * DD + i0 + c];
    }
    __syncthreads();
#pragma unroll
    for (int p = 0; p < 16; p++) {
      float av[4], bv[4];
#pragma unroll
      for (int a = 0; a < 4; a++) av[a] = As[r0 + a][p];
#pragma unroll
      for (int b = 0; b < 4; b++) bv[b] = Bs[p][c0 + b];
#pragma unroll
      for (int a = 0; a < 4; a++)
#pragma unroll
        for (int b = 0; b < 4; b++) acc[a][b] += av[a] * bv[b];
    }
  }
  float uu[4];
#pragma unroll
  for (int b = 0; b < 4; b++) uu[b] = uc[i0 + c0 + b];
#pragma unroll
  for (int a = 0; a < 4; a++) {
    float p = 0.f;
#pragma unroll
    for (int b = 0; b < 4; b++) { float e = acc[a][b] - uu[b]; p += e * e; }
    p += __shfl_xor(p, 1, 64);
    p += __shfl_xor(p, 2, 64);
    p += __shfl_xor(p, 4, 64);
    p += __shfl_xor(p, 8, 64);
    if (tx == 0) atomicAdd(&dout[(size_t)(m0 + r0 + a) * CC + cls], p);
  }
}

__global__ void k_logits(const float* xq2, const float* xqmu, const float* mu2,
                         float* dout) {
  size_t idx = (size_t)blockIdx.x * 256 + threadIdx.x;
  int m = (int)(idx >> 4), c = (int)(idx & 15);
  float q1 = dout[idx];
  float q2 = xq2[m] - 2.0f * xqmu[idx] + mu2[c];
  dout[idx] = -(0.9f * q1 + 0.1f * q2);
}

extern "C" void kernel_launch(void* const* d_in, const int* in_sizes, int n_in,
                              void* d_out, int out_size, void* d_ws, size_t ws_size,
                              hipStream_t stream) {
  (void)in_sizes; (void)n_in; (void)out_size; (void)ws_size;
  const float* X  = (const float*)d_in[0];
  const int*   y  = (const int*)d_in[1];
  const float* Xq = (const float*)d_in[2];
  const float* m  = (const float*)d_in[3];
  const float* kappa = (const float*)d_in[4];
  const float* nu = (const float*)d_in[5];
  const float* td = (const float*)d_in[6];
  const float* tl = (const float*)d_in[7];
  float* out = (float*)d_out;
  float* ws = (float*)d_ws;

  float* Xg    = ws + OFF_XG;
  float* baseb = ws + OFF_BASE;
  float* Lm    = ws + OFF_L;
  float* sigma = ws + OFF_SIGMA;
  float* Dinv  = ws + OFF_DINV;
  float* sums  = ws + OFF_SUMS;
  float* mu    = ws + OFF_MU;
  float* uarr  = ws + OFF_U;
  float* mu2   = ws + OFF_MU2;
  float* xq2   = ws + OFF_XQ2;
  float* xqmu  = ws + OFF_XQMU;
  float* kapnu = ws + OFF_KAPNU;
  float* cf    = ws + OFF_CF;
  float* beta  = ws + OFF_BETA;
  float* invs  = ws + OFF_INVS;
  int* ints    = (int*)(ws + OFF_INTS);
  int* counts  = ints;
  int* offsets = ints + 16;
  int* cursor  = ints + 32;
  int* order   = ints + 48;

  k_scalars<<<1, 256, 0, stream>>>(y, kappa, nu, kapnu, cf, beta, invs,
                                   counts, offsets, cursor, sums, out);
  k_colsums<<<dim3(4, 8), 256, 0, stream>>>(X, y, sums);
  k_mu<<<64, 256, 0, stream>>>(sums, m, kapnu, cf, mu);
  k_mu2<<<16, 256, 0, stream>>>(mu, mu2);
  k_scatter<<<16, 256, 0, stream>>>(y, cursor, order);
  k_gather<<<4096, 256, 0, stream>>>(X, order, Xg);
  k_buildL<<<4096, 256, 0, stream>>>(td, tl, Lm);
  k_base<<<136, 256, 0, stream>>>(Lm, m, kapnu, baseb);
  k_syrk_sigma<<<16 * 136, 256, 0, stream>>>(Xg, baseb, mu, beta, invs,
                                             counts, offsets, sigma);
  for (int k = 0; k < 16; k++) {
    k_chol_diag<<<16, 256, 0, stream>>>(sigma, Dinv, k);
    if (k < 15) {
      k_chol_panel<<<16 * (15 - k), 256, 0, stream>>>(sigma, Dinv, k);
      int nt = (15 - k) * (16 - k) / 2;
      k_chol_syrk<<<16 * nt, 256, 0, stream>>>(sigma, k);
    }
  }
  for (int l = 1; l <= 15; l++)
    k_vlevel<<<16 * (16 - l), 256, 0, stream>>>(sigma, Dinv, l);
  k_finalizeV<<<256, 256, 0, stream>>>(sigma, Dinv);
  k_u<<<64, 256, 0, stream>>>(sigma, mu, uarr);
  k_xqdots<<<4096, 256, 0, stream>>>(Xq, mu, xq2, xqmu);
  k_gemmG_fused<<<dim3(64, 16, 16), 256, 0, stream>>>(Xq, sigma, uarr, out);
  k_logits<<<256, 256, 0, stream>>>(xq2, xqmu, mu2, out);
}

// Round 2
// 4366.910 us; speedup vs baseline: 1.3645x; 1.3645x over previous
//
#include <hip/hip_runtime.h>
#include <math.h>

#define DD 1024
#define NN 4096
#define MM 4096
#define CC 16

typedef _Float16 half8 __attribute__((ext_vector_type(8)));
typedef _Float16 half4 __attribute__((ext_vector_type(4)));
typedef float floatx4 __attribute__((ext_vector_type(4)));

// ---------------- workspace layout (float offsets) ----------------
#define OFF_XG     ((size_t)0)          // 4096*1024  (reused as fp16 UT after syrk)
#define OFF_BASE   ((size_t)4194304)    // 1024*1024
#define OFF_L      ((size_t)5242880)    // 1024*1024
#define OFF_SIGMA  ((size_t)6291456)    // 16*1024*1024
#define OFF_DINV   ((size_t)23068672)   // 16*16*64*64
#define OFF_SUMS   ((size_t)24117248)   // 16*1024
#define OFF_MU     ((size_t)24133632)   // 16*1024
#define OFF_U      ((size_t)24150016)   // 16*1024
#define OFF_MU2    ((size_t)24166400)   // 16
#define OFF_XQ2    ((size_t)24166416)   // 4096
#define OFF_XQMU   ((size_t)24170512)   // 4096*16
#define OFF_KAPNU  ((size_t)24236048)   // 2
#define OFF_CF     ((size_t)24236056)   // 16
#define OFF_BETA   ((size_t)24236072)   // 16
#define OFF_INVS   ((size_t)24236088)   // 16
#define OFF_INTS   ((size_t)24236104)   // ints: counts16, offsets16, cursor16, order4096

__device__ __forceinline__ void tri_decode(int b, int& ti, int& tj) {
  int t = 0;
  while ((t + 1) * (t + 2) / 2 <= b) t++;
  ti = t;
  tj = b - t * (t + 1) / 2;
}

__device__ __forceinline__ float reduce256(float v, float* scratch) {
  for (int o = 32; o > 0; o >>= 1) v += __shfl_down(v, o, 64);
  int lane = threadIdx.x & 63, w = threadIdx.x >> 6;
  __syncthreads();
  if (lane == 0) scratch[w] = v;
  __syncthreads();
  return scratch[0] + scratch[1] + scratch[2] + scratch[3];
}

// ---------------- stats ----------------
__global__ void k_scalars(const int* y, const float* kappa, const float* nu,
                          float* kapnu, float* cf, float* beta, float* invs,
                          int* counts, int* offsets, int* cursor, float* sums,
                          float* dout) {
  __shared__ int h[CC];
  int t = threadIdx.x;
  if (t < CC) h[t] = 0;
  __syncthreads();
  for (int n = t; n < NN; n += 256) atomicAdd(&h[y[n]], 1);
  __syncthreads();
  if (t == 0) {
    float kap = fabsf(kappa[0]) + 1e-6f;
    float nu_ = fmaxf(nu[0], (float)DD - 1.0f + 1e-6f);
    kapnu[0] = kap; kapnu[1] = nu_;
    int off = 0;
    for (int c = 0; c < CC; c++) {
      counts[c] = h[c]; offsets[c] = off; cursor[c] = off; off += h[c];
      cf[c] = (float)h[c];
      beta[c] = kap + (float)h[c];
      invs[c] = 1.0f / (nu_ + (float)h[c] + (float)DD + 2.0f);
    }
  }
  for (size_t i = t; i < (size_t)CC * DD; i += 256) sums[i] = 0.f;
  for (size_t i = t; i < (size_t)MM * CC; i += 256) dout[i] = 0.f;
}

__global__ void k_colsums(const float* X, const int* y, float* sums) {
  __shared__ float acc[CC][256];
  int t = threadIdx.x;
  int col = blockIdx.x * 256 + t;
  for (int c = 0; c < CC; c++) acc[c][t] = 0.f;
  int r0 = blockIdx.y * 128;
  for (int r = r0; r < r0 + 128; r++) {
    int c = y[r];
    acc[c][t] += X[(size_t)r * DD + col];
  }
  for (int c = 0; c < CC; c++) atomicAdd(&sums[(size_t)c * DD + col], acc[c][t]);
}

__global__ void k_mu(const float* sums, const float* m, const float* kapnu,
                     const float* cf, float* mu) {
  int i = blockIdx.x * 256 + threadIdx.x;
  int c = i >> 10, j = i & 1023;
  float kap = kapnu[0];
  mu[i] = (kap * m[j] + sums[i]) / (kap + cf[c]);
}

__global__ void k_mu2(const float* mu, float* mu2) {
  __shared__ float scratch[4];
  int cls = blockIdx.x, t = threadIdx.x;
  float s = 0.f;
  for (int j = t; j < DD; j += 256) {
    float v = mu[(size_t)cls * DD + j];
    s += v * v;
  }
  float tot = reduce256(s, scratch);
  if (t == 0) mu2[cls] = tot;
}

__global__ void k_scatter(const int* y, int* cursor, int* order) {
  int n = blockIdx.x * 256 + threadIdx.x;
  int c = y[n];
  int p = atomicAdd(&cursor[c], 1);
  order[p] = n;
}

__global__ void k_gather(const float* X, const int* order, float* Xg) {
  int p = blockIdx.x;
  int src = order[p];
  for (int j = threadIdx.x; j < DD; j += 256)
    Xg[(size_t)p * DD + j] = X[(size_t)src * DD + j];
}

__global__ void k_buildL(const float* td, const float* tl, float* L) {
  size_t idx = (size_t)blockIdx.x * 256 + threadIdx.x;
  int i = (int)(idx >> 10), j = (int)(idx & 1023);
  float v;
  if (i == j) v = fabsf(td[i]);
  else if (i > j) v = tl[idx];
  else v = 0.f;
  L[idx] = v;
}

// base = L*L^T + kap*m*m^T  (lower tiles only, diag tiles full)
__global__ void k_base(const float* L, const float* m, const float* kapnu, float* base) {
  int ti, tj; tri_decode(blockIdx.x, ti, tj);
  __shared__ float Ta[16][65], Tb[16][65];
  int t = threadIdx.x, tx = t & 15, ty = t >> 4;
  int r0 = ty * 4, c0 = tx * 4;
  float acc[4][4] = {};
  int kmax = (tj + 1) * 64;
  for (int kk = 0; kk < kmax; kk += 16) {
    __syncthreads();
    for (int idx = t; idx < 64 * 16; idx += 256) {
      int r = idx >> 4, p = idx & 15;
      Ta[p][r] = L[(size_t)(ti * 64 + r) * DD + kk + p];
      Tb[p][r] = L[(size_t)(tj * 64 + r) * DD + kk + p];
    }
    __syncthreads();
#pragma unroll
    for (int p = 0; p < 16; p++) {
      float av[4], bv[4];
#pragma unroll
      for (int a = 0; a < 4; a++) av[a] = Ta[p][r0 + a];
#pragma unroll
      for (int b = 0; b < 4; b++) bv[b] = Tb[p][c0 + b];
#pragma unroll
      for (int a = 0; a < 4; a++)
#pragma unroll
        for (int b = 0; b < 4; b++) acc[a][b] += av[a] * bv[b];
    }
  }
  float kap = kapnu[0];
#pragma unroll
  for (int a = 0; a < 4; a++)
#pragma unroll
    for (int b = 0; b < 4; b++) {
      int gi = ti * 64 + r0 + a, gj = tj * 64 + c0 + b;
      base[(size_t)gi * DD + gj] = acc[a][b] + kap * m[gi] * m[gj];
    }
}

// sigma_c = (base + X_c^T X_c - beta*mu*mu^T) * invs   (lower tiles, diag full)
__global__ void k_syrk_sigma(const float* Xg, const float* base, const float* mu,
                             const float* beta, const float* invs,
                             const int* counts, const int* offsets, float* sigma) {
  int b = blockIdx.x;
  int cls = b / 136, tr = b % 136;
  int ti, tj; tri_decode(tr, ti, tj);
  int cnt = counts[cls], off = offsets[cls];
  float* Sg = sigma + (size_t)cls * DD * DD;
  const float* muc = mu + (size_t)cls * DD;
  __shared__ float Xa[16][65], Xb[16][65];
  int t = threadIdx.x, tx = t & 15, ty = t >> 4;
  int r0 = ty * 4, c0 = tx * 4;
  float acc[4][4] = {};
  for (int kk = 0; kk < cnt; kk += 16) {
    __syncthreads();
    for (int idx = t; idx < 16 * 64; idx += 256) {
      int p = idx >> 6, rc = idx & 63;
      int row = kk + p;
      float va = 0.f, vb = 0.f;
      if (row < cnt) {
        va = Xg[(size_t)(off + row) * DD + ti * 64 + rc];
        vb = Xg[(size_t)(off + row) * DD + tj * 64 + rc];
      }
      Xa[p][rc] = va; Xb[p][rc] = vb;
    }
    __syncthreads();
#pragma unroll
    for (int p = 0; p < 16; p++) {
      float av[4], bv[4];
#pragma unroll
      for (int a = 0; a < 4; a++) av[a] = Xa[p][r0 + a];
#pragma unroll
      for (int b2 = 0; b2 < 4; b2++) bv[b2] = Xb[p][c0 + b2];
#pragma unroll
      for (int a = 0; a < 4; a++)
#pragma unroll
        for (int b2 = 0; b2 < 4; b2++) acc[a][b2] += av[a] * bv[b2];
    }
  }
  float bet = beta[cls], isc = invs[cls];
#pragma unroll
  for (int a = 0; a < 4; a++)
#pragma unroll
    for (int b2 = 0; b2 < 4; b2++) {
      int gi = ti * 64 + r0 + a, gj = tj * 64 + c0 + b2;
      float v = acc[a][b2] + base[(size_t)gi * DD + gj] - bet * muc[gi] * muc[gj];
      Sg[(size_t)gi * DD + gj] = v * isc;
    }
}

// ---------------- batched blocked Cholesky (NB=64) ----------------
__global__ void k_chol_diag(float* sigma, float* Dinv, int k) {
  int cls = blockIdx.x;
  float* Sg = sigma + (size_t)cls * DD * DD;
  __shared__ float A[64][65];
  __shared__ float W[64][65];
  int t = threadIdx.x;
  for (int idx = t; idx < 4096; idx += 256) {
    int r = idx >> 6, c = idx & 63;
    A[r][c] = Sg[(size_t)(k * 64 + r) * DD + k * 64 + c];
    W[r][c] = 0.f;
  }
  __syncthreads();
  for (int j = 0; j < 64; j++) {
    if (t == 0) A[j][j] = sqrtf(A[j][j]);
    __syncthreads();
    float rpj = 1.0f / A[j][j];
    for (int r = j + 1 + t; r < 64; r += 256) A[r][j] *= rpj;
    __syncthreads();
    for (int idx = t; idx < 4096; idx += 256) {
      int r = idx >> 6, c = idx & 63;
      if (r > j && c > j) A[r][c] -= A[r][j] * A[c][j];
    }
    __syncthreads();
  }
  if (t < 64) {
    int j = t;
    W[j][j] = 1.0f / A[j][j];
    for (int i = j + 1; i < 64; i++) {
      float s = 0.f;
      for (int kk = j; kk < i; kk++) s += A[i][kk] * W[kk][j];
      W[i][j] = -s / A[i][i];
    }
  }
  __syncthreads();
  for (int idx = t; idx < 4096; idx += 256) {
    int r = idx >> 6, c = idx & 63;
    Sg[(size_t)(k * 64 + r) * DD + k * 64 + c] = (c <= r) ? A[r][c] : 0.f;
    Dinv[((size_t)cls * 16 + k) * 4096 + idx] = W[r][c];
  }
}

__global__ void k_chol_panel(float* sigma, const float* Dinv, int k) {
  int nb = 15 - k;
  int cls = blockIdx.x / nb, sub = blockIdx.x % nb;
  int it = k + 1 + sub;
  float* Sg = sigma + (size_t)cls * DD * DD;
  __shared__ float At[64][65], Di[64][65];
  int t = threadIdx.x, tx = t & 15, ty = t >> 4;
  int r0 = ty * 4, c0 = tx * 4;
  for (int idx = t; idx < 4096; idx += 256) {
    int r = idx >> 6, p = idx & 63;
    At[r][p] = Sg[(size_t)(it * 64 + r) * DD + k * 64 + p];
    Di[r][p] = Dinv[((size_t)cls * 16 + k) * 4096 + idx];
  }
  __syncthreads();
  float acc[4][4] = {};
#pragma unroll 8
  for (int p = 0; p < 64; p++) {
    float av[4], bv[4];
#pragma unroll
    for (int a = 0; a < 4; a++) av[a] = At[r0 + a][p];
#pragma unroll
    for (int b = 0; b < 4; b++) bv[b] = Di[c0 + b][p];
#pragma unroll
    for (int a = 0; a < 4; a++)
#pragma unroll
      for (int b = 0; b < 4; b++) acc[a][b] += av[a] * bv[b];
  }
#pragma unroll
  for (int a = 0; a < 4; a++)
#pragma unroll
    for (int b = 0; b < 4; b++)
      Sg[(size_t)(it * 64 + r0 + a) * DD + k * 64 + c0 + b] = acc[a][b];
}

__global__ void k_chol_syrk(float* sigma, int k) {
  int nrem = 15 - k;
  int nt = nrem * (nrem + 1) / 2;
  int cls = blockIdx.x / nt, s = blockIdx.x % nt;
  int a_, b_; tri_decode(s, a_, b_);
  int it = k + 1 + a_, jt = k + 1 + b_;
  float* Sg = sigma + (size_t)cls * DD * DD;
  __shared__ float La[64][65], Lb[64][65];
  int t = threadIdx.x, tx = t & 15, ty = t >> 4;
  int r0 = ty * 4, c0 = tx * 4;
  for (int idx = t; idx < 4096; idx += 256) {
    int r = idx >> 6, p = idx & 63;
    La[r][p] = Sg[(size_t)(it * 64 + r) * DD + k * 64 + p];
    Lb[r][p] = Sg[(size_t)(jt * 64 + r) * DD + k * 64 + p];
  }
  __syncthreads();
  float acc[4][4] = {};
#pragma unroll 8
  for (int p = 0; p < 64; p++) {
    float av[4], bv[4];
#pragma unroll
    for (int a = 0; a < 4; a++) av[a] = La[r0 + a][p];
#pragma unroll
    for (int b = 0; b < 4; b++) bv[b] = Lb[c0 + b][p];
#pragma unroll
    for (int a = 0; a < 4; a++)
#pragma unroll
      for (int b = 0; b < 4; b++) acc[a][b] += av[a] * bv[b];
  }
#pragma unroll
  for (int a = 0; a < 4; a++)
#pragma unroll
    for (int b = 0; b < 4; b++) {
      size_t addr = (size_t)(it * 64 + r0 + a) * DD + jt * 64 + c0 + b;
      Sg[addr] -= acc[a][b];
    }
}

// ---------------- V = R^{-1}, stored transposed in upper triangle ----------------
__global__ void k_vlevel(float* sigma, const float* Dinv, int l) {
  int nb = 16 - l;
  int cls = blockIdx.x / nb, j = blockIdx.x % nb;
  int i = j + l;
  float* Sg = sigma + (size_t)cls * DD * DD;
  const float* Dv = Dinv + (size_t)cls * 16 * 4096;
  __shared__ float Ta[64][65], Tb[64][65], Ts[64][65];
  int t = threadIdx.x, tx = t & 15, ty = t >> 4;
  int r0 = ty * 4, c0 = tx * 4;
  float acc[4][4] = {};
  for (int k2 = j; k2 < i; k2++) {
    __syncthreads();
    for (int idx = t; idx < 4096; idx += 256) {
      int r = idx >> 6, p = idx & 63;
      Ta[r][p] = Sg[(size_t)(i * 64 + r) * DD + k2 * 64 + p];
    }
    if (k2 == j) {
      for (int idx = t; idx < 4096; idx += 256) {
        int p = idx >> 6, c = idx & 63;
        Tb[c][p] = Dv[(size_t)j * 4096 + idx];
      }
    } else {
      for (int idx = t; idx < 4096; idx += 256) {
        int c = idx >> 6, p = idx & 63;
        Tb[c][p] = Sg[(size_t)(j * 64 + c) * DD + k2 * 64 + p];
      }
    }
    __syncthreads();
#pragma unroll 8
    for (int p = 0; p < 64; p++) {
      float av[4], bv[4];
#pragma unroll
      for (int a = 0; a < 4; a++) av[a] = Ta[r0 + a][p];
#pragma unroll
      for (int b = 0; b < 4; b++) bv[b] = Tb[c0 + b][p];
#pragma unroll
      for (int a = 0; a < 4; a++)
#pragma unroll
        for (int b = 0; b < 4; b++) acc[a][b] += av[a] * bv[b];
    }
  }
  __syncthreads();
#pragma unroll
  for (int a = 0; a < 4; a++)
#pragma unroll
    for (int b = 0; b < 4; b++) Ts[r0 + a][c0 + b] = acc[a][b];
  for (int idx = t; idx < 4096; idx += 256) {
    int r = idx >> 6, p = idx & 63;
    Ta[r][p] = Dv[(size_t)i * 4096 + idx];
  }
  __syncthreads();
  float acc2[4][4] = {};
#pragma unroll 8
  for (int p = 0; p < 64; p++) {
    float av[4], bv[4];
#pragma unroll
    for (int a = 0; a < 4; a++) av[a] = Ta[r0 + a][p];
#pragma unroll
    for (int b = 0; b < 4; b++) bv[b] = Ts[p][c0 + b];
#pragma unroll
    for (int a = 0; a < 4; a++)
#pragma unroll
      for (int b = 0; b < 4; b++) acc2[a][b] += av[a] * bv[b];
  }
  __syncthreads();
#pragma unroll
  for (int a = 0; a < 4; a++)
#pragma unroll
    for (int b = 0; b < 4; b++) Ts[r0 + a][c0 + b] = -acc2[a][b];
  __syncthreads();
  for (int idx = t; idx < 4096; idx += 256) {
    int rr = idx & 63, cc = idx >> 6;
    Sg[(size_t)(j * 64 + cc) * DD + i * 64 + rr] = Ts[rr][cc];
  }
}

__global__ void k_finalizeV(float* sigma, const float* Dinv) {
  int cls = blockIdx.x >> 4, i = blockIdx.x & 15;
  float* Sg = sigma + (size_t)cls * DD * DD;
  const float* Dv = Dinv + ((size_t)cls * 16 + i) * 4096;
  for (int idx = threadIdx.x; idx < 4096; idx += 256) {
    int a = idx >> 6, b = idx & 63;
    Sg[(size_t)(i * 64 + a) * DD + i * 64 + b] = Dv[b * 64 + a];
  }
}

// u_c = V * mu_c  (via U = V^T stored in sigma)
__global__ void k_u(const float* sigma, const float* mu, float* u) {
  int cls = blockIdx.x >> 2, blk = blockIdx.x & 3;
  int i = blk * 256 + threadIdx.x;
  const float* Ug = sigma + (size_t)cls * DD * DD;
  const float* muc = mu + (size_t)cls * DD;
  float s = 0.f;
  for (int j = 0; j <= i; j++) s += Ug[(size_t)j * DD + i] * muc[j];
  u[(size_t)cls * DD + i] = s;
}

// UT[cls][n][k] = (k<=n) ? sigma[cls][k][n] : 0, as fp16 (64x64 LDS transpose tiles)
__global__ void k_transU(const float* sigma, _Float16* UT) {
  int nblk = blockIdx.x, kblk = blockIdx.y, cls = blockIdx.z;
  _Float16* outp = UT + ((size_t)cls << 20);
  int t = threadIdx.x;
  if (kblk > nblk) {
    for (int i = 0; i < 2; i++) {
      int lin = i * 256 + t;
      int r = lin >> 3, c8 = lin & 7;
      half8 z = {};
      *(half8*)&outp[(size_t)(nblk * 64 + r) * DD + kblk * 64 + c8 * 8] = z;
    }
    return;
  }
  __shared__ float T[64][65];
  const float* Sg = sigma + ((size_t)cls << 20);
  for (int i = 0; i < 16; i++) {
    int lin = i * 256 + t;
    int a = lin >> 6, b = lin & 63;
    T[a][b] = Sg[(size_t)(kblk * 64 + a) * DD + nblk * 64 + b];
  }
  __syncthreads();
  for (int i = 0; i < 4; i++) {
    int lin = i * 256 + t;
    int r = lin >> 4, c4 = lin & 15;
    half4 h;
#pragma unroll
    for (int j2 = 0; j2 < 4; j2++) h[j2] = (_Float16)T[c4 * 4 + j2][r];
    *(half4*)&outp[(size_t)(nblk * 64 + r) * DD + kblk * 64 + c4 * 4] = h;
  }
}

__global__ void k_xqdots(const float* Xq, const float* mu, float* xq2, float* xqmu) {
  __shared__ float xrow[DD];
  __shared__ float scratch[4];
  int m = blockIdx.x, t = threadIdx.x;
  for (int j = t; j < DD; j += 256) xrow[j] = Xq[(size_t)m * DD + j];
  __syncthreads();
  float s2 = 0.f;
  for (int j = t; j < DD; j += 256) s2 += xrow[j] * xrow[j];
  float tot = reduce256(s2, scratch);
  if (t == 0) xq2[m] = tot;
  for (int c = 0; c < CC; c++) {
    float s = 0.f;
    for (int j = t; j < DD; j += 256) s += xrow[j] * mu[(size_t)c * DD + j];
    tot = reduce256(s, scratch);
    if (t == 0) xqmu[(size_t)m * CC + c] = tot;
  }
}

// MFMA fp16 GEMM: G = Xq * U (per class), fused epilogue: atomicAdd ||G_row - u||^2
// 128x128 tile, 4 waves of 4x4 16x16x32 frags, triangular K bound.
__global__ __launch_bounds__(256) void k_gemmG_mfma(const float* Xq, const _Float16* UT,
                                                    const float* u, float* dout) {
  int mt = blockIdx.x, ct = blockIdx.y, cls = blockIdx.z;
  const _Float16* Ug = UT + ((size_t)cls << 20);
  __shared__ _Float16 As[128][40];
  __shared__ _Float16 Bs[128][40];
  int t = threadIdx.x;
  int wave = t >> 6, lane = t & 63;
  int wr = wave >> 1, wc = wave & 1;
  int quad = lane >> 4, l15 = lane & 15;
  int m0 = mt * 128, n0 = ct * 128;
  floatx4 acc[4][4];
#pragma unroll
  for (int a = 0; a < 4; a++)
#pragma unroll
    for (int b = 0; b < 4; b++) acc[a][b] = (floatx4){0.f, 0.f, 0.f, 0.f};
  int kmax = (ct + 1) * 128;
  for (int kk = 0; kk < kmax; kk += 32) {
    __syncthreads();
#pragma unroll
    for (int i = 0; i < 4; i++) {
      int lin = i * 256 + t;
      int r = lin >> 3, c4 = lin & 7;
      floatx4 v = *(const floatx4*)&Xq[(size_t)(m0 + r) * DD + kk + c4 * 4];
      half4 h;
      h[0] = (_Float16)v[0]; h[1] = (_Float16)v[1];
      h[2] = (_Float16)v[2]; h[3] = (_Float16)v[3];
      *(half4*)&As[r][c4 * 4] = h;
    }
#pragma unroll
    for (int i = 0; i < 2; i++) {
      int lin = i * 256 + t;
      int n = lin >> 2, c8 = lin & 3;
      *(half8*)&Bs[n][c8 * 8] = *(const half8*)&Ug[(size_t)(n0 + n) * DD + kk + c8 * 8];
    }
    __syncthreads();
    half8 af[4], bf[4];
#pragma unroll
    for (int f = 0; f < 4; f++) {
      af[f] = *(const half8*)&As[wr * 64 + f * 16 + l15][quad * 8];
      bf[f] = *(const half8*)&Bs[wc * 64 + f * 16 + l15][quad * 8];
    }
#pragma unroll
    for (int fi = 0; fi < 4; fi++)
#pragma unroll
      for (int fj = 0; fj < 4; fj++)
        acc[fi][fj] = __builtin_amdgcn_mfma_f32_16x16x32_f16(af[fi], bf[fj], acc[fi][fj], 0, 0, 0);
  }
  float uv[4];
#pragma unroll
  for (int fj = 0; fj < 4; fj++)
    uv[fj] = u[(size_t)cls * DD + n0 + wc * 64 + fj * 16 + l15];
#pragma unroll
  for (int fi = 0; fi < 4; fi++) {
#pragma unroll
    for (int r = 0; r < 4; r++) {
      float p = 0.f;
#pragma unroll
      for (int fj = 0; fj < 4; fj++) {
        float e = acc[fi][fj][r] - uv[fj];
        p += e * e;
      }
      p += __shfl_xor(p, 1, 64);
      p += __shfl_xor(p, 2, 64);
      p += __shfl_xor(p, 4, 64);
      p += __shfl_xor(p, 8, 64);
      if (l15 == 0) {
        int m = m0 + wr * 64 + fi * 16 + quad * 4 + r;
        atomicAdd(&dout[(size_t)m * CC + cls], p);
      }
    }
  }
}

__global__ void k_logits(const float* xq2, const float* xqmu, const float* mu2,
                         float* dout) {
  size_t idx = (size_t)blockIdx.x * 256 + threadIdx.x;
  int m = (int)(idx >> 4), c = (int)(idx & 15);
  float q1 = dout[idx];
  float q2 = xq2[m] - 2.0f * xqmu[idx] + mu2[c];
  dout[idx] = -(0.9f * q1 + 0.1f * q2);
}

extern "C" void kernel_launch(void* const* d_in, const int* in_sizes, int n_in,
                              void* d_out, int out_size, void* d_ws, size_t ws_size,
                              hipStream_t stream) {
  (void)in_sizes; (void)n_in; (void)out_size; (void)ws_size;
  const float* X  = (const float*)d_in[0];
  const int*   y  = (const int*)d_in[1];
  const float* Xq = (const float*)d_in[2];
  const float* m  = (const float*)d_in[3];
  const float* kappa = (const float*)d_in[4];
  const float* nu = (const float*)d_in[5];
  const float* td = (const float*)d_in[6];
  const float* tl = (const float*)d_in[7];
  float* out = (float*)d_out;
  float* ws = (float*)d_ws;

  float* Xg    = ws + OFF_XG;
  _Float16* UT = (_Float16*)(ws + OFF_XG);   // reuses Xg region after syrk
  float* baseb = ws + OFF_BASE;
  float* Lm    = ws + OFF_L;
  float* sigma = ws + OFF_SIGMA;
  float* Dinv  = ws + OFF_DINV;
  float* sums  = ws + OFF_SUMS;
  float* mu    = ws + OFF_MU;
  float* uarr  = ws + OFF_U;
  float* mu2   = ws + OFF_MU2;
  float* xq2   = ws + OFF_XQ2;
  float* xqmu  = ws + OFF_XQMU;
  float* kapnu = ws + OFF_KAPNU;
  float* cf    = ws + OFF_CF;
  float* beta  = ws + OFF_BETA;
  float* invs  = ws + OFF_INVS;
  int* ints    = (int*)(ws + OFF_INTS);
  int* counts  = ints;
  int* offsets = ints + 16;
  int* cursor  = ints + 32;
  int* order   = ints + 48;

  k_scalars<<<1, 256, 0, stream>>>(y, kappa, nu, kapnu, cf, beta, invs,
                                   counts, offsets, cursor, sums, out);
  k_colsums<<<dim3(4, 32), 256, 0, stream>>>(X, y, sums);
  k_mu<<<64, 256, 0, stream>>>(sums, m, kapnu, cf, mu);
  k_mu2<<<16, 256, 0, stream>>>(mu, mu2);
  k_scatter<<<16, 256, 0, stream>>>(y, cursor, order);
  k_gather<<<4096, 256, 0, stream>>>(X, order, Xg);
  k_buildL<<<4096, 256, 0, stream>>>(td, tl, Lm);
  k_base<<<136, 256, 0, stream>>>(Lm, m, kapnu, baseb);
  k_syrk_sigma<<<16 * 136, 256, 0, stream>>>(Xg, baseb, mu, beta, invs,
                                             counts, offsets, sigma);
  for (int k = 0; k < 16; k++) {
    k_chol_diag<<<16, 256, 0, stream>>>(sigma, Dinv, k);
    if (k < 15) {
      k_chol_panel<<<16 * (15 - k), 256, 0, stream>>>(sigma, Dinv, k);
      int nt = (15 - k) * (16 - k) / 2;
      k_chol_syrk<<<16 * nt, 256, 0, stream>>>(sigma, k);
    }
  }
  for (int l = 1; l <= 15; l++)
    k_vlevel<<<16 * (16 - l), 256, 0, stream>>>(sigma, Dinv, l);
  k_finalizeV<<<256, 256, 0, stream>>>(sigma, Dinv);
  k_u<<<64, 256, 0, stream>>>(sigma, mu, uarr);
  k_transU<<<dim3(16, 16, 16), 256, 0, stream>>>(sigma, UT);
  k_xqdots<<<4096, 256, 0, stream>>>(Xq, mu, xq2, xqmu);
  k_gemmG_mfma<<<dim3(32, 8, 16), 256, 0, stream>>>(Xq, UT, uarr, out);
  k_logits<<<256, 256, 0, stream>>>(xq2, xqmu, mu2, out);
}

// Round 4
// 3836.646 us; speedup vs baseline: 1.5530x; 1.1382x over previous
//
#include <hip/hip_runtime.h>
#include <math.h>

#define DD 1024
#define NP 4608   // padded sample pitch (class offsets padded to 32)

typedef _Float16 half8 __attribute__((ext_vector_type(8)));
typedef _Float16 half4 __attribute__((ext_vector_type(4)));
typedef float floatx4 __attribute__((ext_vector_type(4)));
typedef short s16x8 __attribute__((ext_vector_type(8)));

// ---------------- workspace layout (float offsets) ----------------
// XT hi/lo bf16 planes live in [0, 4718592); UT (packed fp16 V tiles,
// 4456448 float-slots) overlays the same region after the SYRK consumes XT.
#define OFF_XTH   ((size_t)0)
#define OFF_XTL   ((size_t)2359296)
#define OFF_BASE  ((size_t)4718592)    // float[1024][1024]
#define OFF_SIGMA ((size_t)5767168)    // 16*1024*1024 fp32; first 1M floats double as L (dead before syrk)
#define OFF_DINV  ((size_t)22544384)   // 16*16*64*64 fp32
#define OFF_SUMS  ((size_t)23592960)
#define OFF_MU    ((size_t)23609344)
#define OFF_U     ((size_t)23625728)
#define OFF_MU2   ((size_t)23642112)
#define OFF_XQ2   ((size_t)23642128)
#define OFF_XQMU  ((size_t)23646224)
#define OFF_KAPNU ((size_t)23711760)
#define OFF_CF    ((size_t)23711762)
#define OFF_BETA  ((size_t)23711778)
#define OFF_INVS  ((size_t)23711794)
#define OFF_INTS  ((size_t)23711810)   // ints: counts16, offsets16, cursor16, order[4608]

#define UT_CLS_STRIDE ((size_t)557056) // 136 tiles * 4096 halves

__device__ __forceinline__ void tri_decode(int b, int& ti, int& tj) {
  int t = 0;
  while ((t + 1) * (t + 2) / 2 <= b) t++;
  ti = t;
  tj = b - t * (t + 1) / 2;
}

__device__ __forceinline__ short f2bf(float f) {
  union { float f; unsigned u; } v; v.f = f;
  unsigned r = v.u + 0x7FFF + ((v.u >> 16) & 1);
  return (short)(r >> 16);
}
__device__ __forceinline__ float bf2f(short b) {
  union { unsigned u; float f; } v; v.u = ((unsigned)(unsigned short)b) << 16; return v.f;
}

__device__ __forceinline__ float reduce256(float v, float* scratch) {
  for (int o = 32; o > 0; o >>= 1) v += __shfl_down(v, o, 64);
  int lane = threadIdx.x & 63, w = threadIdx.x >> 6;
  __syncthreads();
  if (lane == 0) scratch[w] = v;
  __syncthreads();
  return scratch[0] + scratch[1] + scratch[2] + scratch[3];
}

// ---------------- stats ----------------
__global__ void k_scalars(const int* y, const float* kappa, const float* nu,
                          float* kapnu, float* cf, float* beta, float* invs,
                          int* counts, int* offsets, int* cursor, int* order,
                          float* sums) {
  __shared__ int h[16];
  int t = threadIdx.x;
  if (t < 16) h[t] = 0;
  __syncthreads();
  for (int n = t; n < 4096; n += 256) atomicAdd(&h[y[n]], 1);
  __syncthreads();
  if (t == 0) {
    float kap = fabsf(kappa[0]) + 1e-6f;
    float nu_ = fmaxf(nu[0], 1024.0f - 1.0f + 1e-6f);
    kapnu[0] = kap; kapnu[1] = nu_;
    int off = 0;
    for (int c = 0; c < 16; c++) {
      counts[c] = h[c]; offsets[c] = off; cursor[c] = off;
      cf[c] = (float)h[c];
      beta[c] = kap + (float)h[c];
      invs[c] = 1.0f / (nu_ + (float)h[c] + 1024.0f + 2.0f);
      off += (h[c] + 31) & ~31;
    }
  }
  for (int i = t; i < 16 * 1024; i += 256) sums[i] = 0.f;
  for (int i = t; i < NP; i += 256) order[i] = -1;
}

__global__ void k_colsums(const float* X, const int* y, float* sums) {
  __shared__ float acc[16][256];
  int t = threadIdx.x;
  int col = blockIdx.x * 256 + t;
  for (int c = 0; c < 16; c++) acc[c][t] = 0.f;
  int r0 = blockIdx.y * 128;
  for (int r = r0; r < r0 + 128; r++) {
    int c = y[r];
    acc[c][t] += X[(size_t)r * DD + col];
  }
  for (int c = 0; c < 16; c++) atomicAdd(&sums[(size_t)c * DD + col], acc[c][t]);
}

__global__ void k_mu(const float* sums, const float* m, const float* kapnu,
                     const float* cf, float* mu) {
  int i = blockIdx.x * 256 + threadIdx.x;
  int c = i >> 10, j = i & 1023;
  float kap = kapnu[0];
  mu[i] = (kap * m[j] + sums[i]) / (kap + cf[c]);
}

__global__ void k_mu2(const float* mu, float* mu2) {
  __shared__ float scratch[4];
  int cls = blockIdx.x, t = threadIdx.x;
  float s = 0.f;
  for (int j = t; j < DD; j += 256) {
    float v = mu[(size_t)cls * DD + j];
    s += v * v;
  }
  float tot = reduce256(s, scratch);
  if (t == 0) mu2[cls] = tot;
}

__global__ void k_scatter(const int* y, int* cursor, int* order) {
  int n = blockIdx.x * 256 + threadIdx.x;
  int c = y[n];
  int p = atomicAdd(&cursor[c], 1);
  order[p] = n;
}

// X -> transposed, class-grouped, bf16 hi/lo planes [1024][NP]
__global__ void k_gatherT(const float* X, const int* order, short* XTh, short* XTl) {
  int pt = blockIdx.x, dt = blockIdx.y, t = threadIdx.x;
  __shared__ float T[64 * 66];
  __shared__ int src[64];
  if (t < 64) src[t] = order[pt * 64 + t];
  __syncthreads();
  for (int i = 0; i < 16; i++) {
    int lin = i * 256 + t;
    int r = lin >> 6, c = lin & 63;
    int s = src[r];
    T[r * 66 + c] = (s >= 0) ? X[(size_t)s * DD + dt * 64 + c] : 0.f;
  }
  __syncthreads();
  for (int i = 0; i < 16; i++) {
    int lin = i * 256 + t;
    int d = lin >> 6, p = lin & 63;
    float v = T[p * 66 + d];
    short hi = f2bf(v);
    float lov = v - bf2f(hi);
    size_t addr = (size_t)(dt * 64 + d) * NP + pt * 64 + p;
    XTh[addr] = hi;
    XTl[addr] = f2bf(lov);
  }
}

__global__ void k_buildL(const float* td, const float* tl, float* L) {
  size_t idx = (size_t)blockIdx.x * 256 + threadIdx.x;
  int i = (int)(idx >> 10), j = (int)(idx & 1023);
  float v;
  if (i == j) v = fabsf(td[i]);
  else if (i > j) v = tl[idx];
  else v = 0.f;
  L[idx] = v;
}

// base = L*L^T + kap*m*m^T  (fp32, lower 64-tiles, diag full) — R2-proven body
__global__ void k_base(const float* L, const float* m, const float* kapnu, float* base) {
  int ti, tj; tri_decode(blockIdx.x, ti, tj);
  __shared__ float Ta[16][65], Tb[16][65];
  int t = threadIdx.x, tx = t & 15, ty = t >> 4;
  int r0 = ty * 4, c0 = tx * 4;
  float acc[4][4] = {};
  int kmax = (tj + 1) * 64;
  for (int kk = 0; kk < kmax; kk += 16) {
    __syncthreads();
    for (int idx = t; idx < 64 * 16; idx += 256) {
      int r = idx >> 4, p = idx & 15;
      Ta[p][r] = L[(size_t)(ti * 64 + r) * DD + kk + p];
      Tb[p][r] = L[(size_t)(tj * 64 + r) * DD + kk + p];
    }
    __syncthreads();
#pragma unroll
    for (int p = 0; p < 16; p++) {
      float av[4], bv[4];
#pragma unroll
      for (int a = 0; a < 4; a++) av[a] = Ta[p][r0 + a];
#pragma unroll
      for (int b = 0; b < 4; b++) bv[b] = Tb[p][c0 + b];
#pragma unroll
      for (int a = 0; a < 4; a++)
#pragma unroll
        for (int b = 0; b < 4; b++) acc[a][b] += av[a] * bv[b];
    }
  }
  float kap = kapnu[0];
#pragma unroll
  for (int a = 0; a < 4; a++)
#pragma unroll
    for (int b = 0; b < 4; b++) {
      int gi = ti * 64 + r0 + a, gj = tj * 64 + c0 + b;
      base[(size_t)gi * DD + gj] = acc[a][b] + kap * m[gi] * m[gj];
    }
}

// sigma = (base + X^T X - beta*mu*mu^T) * invs, bf16-split MFMA, lower 128-tiles
__global__ __launch_bounds__(256) void k_syrk_mfma(const short* XTh, const short* XTl,
                                                   const float* base, const float* mu,
                                                   const float* beta, const float* invs,
                                                   const int* counts, const int* offsets,
                                                   float* sigma) {
  int bb = blockIdx.x;
  int cls = bb / 36, tr = bb % 36;
  int ti, tj; tri_decode(tr, ti, tj);
  int cnt = counts[cls], off = offsets[cls];
  float* Sg = sigma + ((size_t)cls << 20);
  const float* muc = mu + (size_t)cls * DD;
  __shared__ short Ah[128 * 40], Al[128 * 40], Bh[128 * 40], Bl[128 * 40];
  int t = threadIdx.x;
  int wave = t >> 6, lane = t & 63;
  int wr = wave >> 1, wc = wave & 1;
  int quad = lane >> 4, l15 = lane & 15;
  int i0 = ti * 128, j0 = tj * 128;
  bool same = (ti == tj);
  floatx4 acc[4][4];
#pragma unroll
  for (int a = 0; a < 4; a++)
#pragma unroll
    for (int b = 0; b < 4; b++) acc[a][b] = (floatx4){0.f, 0.f, 0.f, 0.f};
  for (int nn = 0; nn < cnt; nn += 32) {
    __syncthreads();
#pragma unroll
    for (int r = 0; r < 2; r++) {
      int lin = r * 256 + t;
      int row = lin >> 2, kg = (lin & 3) << 3;
      size_t sA = (size_t)(i0 + row) * NP + off + nn + kg;
      *(s16x8*)&Ah[row * 40 + kg] = *(const s16x8*)&XTh[sA];
      *(s16x8*)&Al[row * 40 + kg] = *(const s16x8*)&XTl[sA];
      if (!same) {
        size_t sB = (size_t)(j0 + row) * NP + off + nn + kg;
        *(s16x8*)&Bh[row * 40 + kg] = *(const s16x8*)&XTh[sB];
        *(s16x8*)&Bl[row * 40 + kg] = *(const s16x8*)&XTl[sB];
      }
    }
    __syncthreads();
    const short* PBh = same ? Ah : Bh;
    const short* PBl = same ? Al : Bl;
    s16x8 ah[4], al[4], bh[4], bl[4];
#pragma unroll
    for (int f = 0; f < 4; f++) {
      ah[f] = *(const s16x8*)&Ah[(wr * 64 + f * 16 + l15) * 40 + quad * 8];
      al[f] = *(const s16x8*)&Al[(wr * 64 + f * 16 + l15) * 40 + quad * 8];
      bh[f] = *(const s16x8*)&PBh[(wc * 64 + f * 16 + l15) * 40 + quad * 8];
      bl[f] = *(const s16x8*)&PBl[(wc * 64 + f * 16 + l15) * 40 + quad * 8];
    }
#pragma unroll
    for (int fi = 0; fi < 4; fi++)
#pragma unroll
      for (int fj = 0; fj < 4; fj++) {
        acc[fi][fj] = __builtin_amdgcn_mfma_f32_16x16x32_bf16(ah[fi], bh[fj], acc[fi][fj], 0, 0, 0);
        acc[fi][fj] = __builtin_amdgcn_mfma_f32_16x16x32_bf16(ah[fi], bl[fj], acc[fi][fj], 0, 0, 0);
        acc[fi][fj] = __builtin_amdgcn_mfma_f32_16x16x32_bf16(al[fi], bh[fj], acc[fi][fj], 0, 0, 0);
      }
  }
  float bet = beta[cls], isc = invs[cls];
#pragma unroll
  for (int fi = 0; fi < 4; fi++)
#pragma unroll
    for (int fj = 0; fj < 4; fj++)
#pragma unroll
      for (int reg = 0; reg < 4; reg++) {
        int gi = i0 + wr * 64 + fi * 16 + quad * 4 + reg;
        int gj = j0 + wc * 64 + fj * 16 + l15;
        float v = acc[fi][fj][reg] + base[(size_t)gi * DD + gj] - bet * muc[gi] * muc[gj];
        Sg[(size_t)gi * DD + gj] = v * isc;
      }
}

// ---------------- factorization device functions (R2-proven bodies) ----------------
// Cholesky of 64x64 tile already in LDS A; writes L tile + W=inv(L) to global.
__device__ void chol_from_lds(float* Sg, float* Dinv, int cls, int k, int t,
                              float* A, float* W) {
  for (int j = 0; j < 64; j++) {
    if (t == 0) A[j * 66 + j] = sqrtf(A[j * 66 + j]);
    __syncthreads();
    float rpj = 1.0f / A[j * 66 + j];
    for (int r = j + 1 + t; r < 64; r += 256) A[r * 66 + j] *= rpj;
    __syncthreads();
    for (int idx = t; idx < 4096; idx += 256) {
      int r = idx >> 6, c = idx & 63;
      if (r > j && c > j) A[r * 66 + c] -= A[r * 66 + j] * A[c * 66 + j];
    }
    __syncthreads();
  }
  for (int idx = t; idx < 4096; idx += 256) {
    int r = idx >> 6, c = idx & 63;
    W[r * 66 + c] = 0.f;
  }
  __syncthreads();
  if (t < 64) {
    int j = t;
    W[j * 66 + j] = 1.0f / A[j * 66 + j];
    for (int i = j + 1; i < 64; i++) {
      float s = 0.f;
      for (int kk = j; kk < i; kk++) s += A[i * 66 + kk] * W[kk * 66 + j];
      W[i * 66 + j] = -s / A[i * 66 + i];
    }
  }
  __syncthreads();
  for (int idx = t; idx < 4096; idx += 256) {
    int r = idx >> 6, c = idx & 63;
    Sg[(size_t)(k * 64 + r) * DD + k * 64 + c] = (c <= r) ? A[r * 66 + c] : 0.f;
    Dinv[((size_t)(cls * 16 + k)) * 4096 + idx] = W[r * 66 + c];
  }
}

__global__ void k_diag0(float* sigma, float* Dinv) {
  __shared__ float A[64 * 66], W[64 * 66];
  int cls = blockIdx.x, t = threadIdx.x;
  float* Sg = sigma + ((size_t)cls << 20);
  for (int idx = t; idx < 4096; idx += 256) {
    int r = idx >> 6, c = idx & 63;
    A[r * 66 + c] = Sg[(size_t)r * DD + c];
  }
  __syncthreads();
  chol_from_lds(Sg, Dinv, cls, 0, t, A, W);
}

// panel: L(it,k) = A(it,k) * W_k^T
__global__ void k_panel(float* sigma, const float* Dinv, int k) {
  int nb = 15 - k;
  int cls = blockIdx.x / nb, sub = blockIdx.x % nb;
  int it = k + 1 + sub;
  float* Sg = sigma + ((size_t)cls << 20);
  __shared__ float At[64 * 66], Di[64 * 66];
  int t = threadIdx.x, tx = t & 15, ty = t >> 4;
  int r0 = ty * 4, c0 = tx * 4;
  for (int idx = t; idx < 4096; idx += 256) {
    int r = idx >> 6, p = idx & 63;
    At[r * 66 + p] = Sg[(size_t)(it * 64 + r) * DD + k * 64 + p];
    Di[r * 66 + p] = Dinv[((size_t)(cls * 16 + k)) * 4096 + idx];
  }
  __syncthreads();
  float acc[4][4] = {};
#pragma unroll 8
  for (int p = 0; p < 64; p++) {
    float av[4], bv[4];
#pragma unroll
    for (int a = 0; a < 4; a++) av[a] = At[(r0 + a) * 66 + p];
#pragma unroll
    for (int b = 0; b < 4; b++) bv[b] = Di[(c0 + b) * 66 + p];
#pragma unroll
    for (int a = 0; a < 4; a++)
#pragma unroll
      for (int b = 0; b < 4; b++) acc[a][b] += av[a] * bv[b];
  }
#pragma unroll
  for (int a = 0; a < 4; a++)
#pragma unroll
    for (int b = 0; b < 4; b++)
      Sg[(size_t)(it * 64 + r0 + a) * DD + k * 64 + c0 + b] = acc[a][b];
}

// trailing update for iteration k; block b<16 also factors tile (k+1,k+1) in LDS
__global__ void k_syrkdiag(float* sigma, float* Dinv, int k) {
  __shared__ float La[64 * 66], Lb[64 * 66], Ts[64 * 66];
  int b = blockIdx.x, t = threadIdx.x;
  int tx = t & 15, ty = t >> 4;
  int r0 = ty * 4, c0 = tx * 4;
  int nb = 15 - k;
  int nt = nb * (nb + 1) / 2;
  int cls, it, jt;
  bool special = (b < 16);
  if (special) {
    cls = b; it = k + 1; jt = k + 1;
  } else {
    int jp = b - 16;
    cls = jp / (nt - 1);
    int s = jp % (nt - 1) + 1;
    int a_, b_; tri_decode(s, a_, b_);
    it = k + 1 + a_; jt = k + 1 + b_;
  }
  float* Sg = sigma + ((size_t)cls << 20);
  for (int idx = t; idx < 4096; idx += 256) {
    int r = idx >> 6, p = idx & 63;
    La[r * 66 + p] = Sg[(size_t)(it * 64 + r) * DD + k * 64 + p];
    Lb[r * 66 + p] = Sg[(size_t)(jt * 64 + r) * DD + k * 64 + p];
  }
  __syncthreads();
  float acc[4][4] = {};
#pragma unroll 8
  for (int p = 0; p < 64; p++) {
    float av[4], bv[4];
#pragma unroll
    for (int a = 0; a < 4; a++) av[a] = La[(r0 + a) * 66 + p];
#pragma unroll
    for (int b2 = 0; b2 < 4; b2++) bv[b2] = Lb[(c0 + b2) * 66 + p];
#pragma unroll
    for (int a = 0; a < 4; a++)
#pragma unroll
      for (int b2 = 0; b2 < 4; b2++) acc[a][b2] += av[a] * bv[b2];
  }
  if (!special) {
#pragma unroll
    for (int a = 0; a < 4; a++)
#pragma unroll
      for (int b2 = 0; b2 < 4; b2++) {
        size_t addr = (size_t)(it * 64 + r0 + a) * DD + jt * 64 + c0 + b2;
        Sg[addr] -= acc[a][b2];
      }
    return;
  }
  // special: updated tile into LDS, then factor + invert (no global round-trip)
  __syncthreads();
#pragma unroll
  for (int a = 0; a < 4; a++)
#pragma unroll
    for (int b2 = 0; b2 < 4; b2++) {
      size_t addr = (size_t)(it * 64 + r0 + a) * DD + jt * 64 + c0 + b2;
      Ts[(r0 + a) * 66 + c0 + b2] = Sg[addr] - acc[a][b2];
    }
  __syncthreads();
  chol_from_lds(Sg, Dinv, cls, k + 1, t, Ts, La);
}

// V = R^{-1}, off-diag tiles stored transposed in sigma's upper triangle
__global__ void k_vlevel(float* sigma, const float* Dinv, int l) {
  int nb = 16 - l;
  int cls = blockIdx.x / nb, j = blockIdx.x % nb;
  int i = j + l;
  float* Sg = sigma + ((size_t)cls << 20);
  const float* Dv = Dinv + (size_t)cls * 16 * 4096;
  __shared__ float Ta[64 * 66], Tb[64 * 66], Ts[64 * 66];
  int t = threadIdx.x, tx = t & 15, ty = t >> 4;
  int r0 = ty * 4, c0 = tx * 4;
  float acc[4][4] = {};
  for (int k2 = j; k2 < i; k2++) {
    __syncthreads();
    for (int idx = t; idx < 4096; idx += 256) {
      int r = idx >> 6, p = idx & 63;
      Ta[r * 66 + p] = Sg[(size_t)(i * 64 + r) * DD + k2 * 64 + p];
    }
    if (k2 == j) {
      for (int idx = t; idx < 4096; idx += 256) {
        int p = idx >> 6, c = idx & 63;
        Tb[c * 66 + p] = Dv[(size_t)j * 4096 + idx];
      }
    } else {
      for (int idx = t; idx < 4096; idx += 256) {
        int c = idx >> 6, p = idx & 63;
        Tb[c * 66 + p] = Sg[(size_t)(j * 64 + c) * DD + k2 * 64 + p];
      }
    }
    __syncthreads();
#pragma unroll 8
    for (int p = 0; p < 64; p++) {
      float av[4], bv[4];
#pragma unroll
      for (int a = 0; a < 4; a++) av[a] = Ta[(r0 + a) * 66 + p];
#pragma unroll
      for (int b = 0; b < 4; b++) bv[b] = Tb[(c0 + b) * 66 + p];
#pragma unroll
      for (int a = 0; a < 4; a++)
#pragma unroll
        for (int b = 0; b < 4; b++) acc[a][b] += av[a] * bv[b];
    }
  }
  __syncthreads();
#pragma unroll
  for (int a = 0; a < 4; a++)
#pragma unroll
    for (int b = 0; b < 4; b++) Ts[(r0 + a) * 66 + c0 + b] = acc[a][b];
  for (int idx = t; idx < 4096; idx += 256) {
    int r = idx >> 6, p = idx & 63;
    Ta[r * 66 + p] = Dv[(size_t)i * 4096 + idx];
  }
  __syncthreads();
  float acc2[4][4] = {};
#pragma unroll 8
  for (int p = 0; p < 64; p++) {
    float av[4], bv[4];
#pragma unroll
    for (int a = 0; a < 4; a++) av[a] = Ta[(r0 + a) * 66 + p];
#pragma unroll
    for (int b = 0; b < 4; b++) bv[b] = Ts[p * 66 + c0 + b];
#pragma unroll
    for (int a = 0; a < 4; a++)
#pragma unroll
      for (int b = 0; b < 4; b++) acc2[a][b] += av[a] * bv[b];
  }
  __syncthreads();
#pragma unroll
  for (int a = 0; a < 4; a++)
#pragma unroll
    for (int b = 0; b < 4; b++) Ts[(r0 + a) * 66 + c0 + b] = -acc2[a][b];
  __syncthreads();
  for (int idx = t; idx < 4096; idx += 256) {
    int rr = idx & 63, cc = idx >> 6;
    Sg[(size_t)(j * 64 + cc) * DD + i * 64 + rr] = Ts[rr * 66 + cc];
  }
}

// jobs: [0,64) u = V*mu chunks; [64,2240) packed-fp16 V tile transpose
__global__ void k_finalize(const float* sigma, const float* Dinv, const float* mu,
                           float* uarr, _Float16* UT) {
  __shared__ float U0[64 * 66];
  int j = blockIdx.x, t = threadIdx.x;
  if (j < 64) {
    int cls = j >> 2, chunk = j & 3;
    int i = chunk * 256 + t;
    int it = i >> 6, li = i & 63;
    const float* Sg = sigma + ((size_t)cls << 20);
    const float* muc = mu + (size_t)cls * DD;
    float s = 0.f;
    int jmax = it * 64;
    for (int j2 = 0; j2 < jmax; j2++) s += Sg[(size_t)j2 * DD + i] * muc[j2];
    const float* Dv = Dinv + ((size_t)(cls * 16 + it)) * 4096 + (size_t)li * 64;
    for (int j2 = 0; j2 <= li; j2++) s += Dv[j2] * muc[jmax + j2];
    uarr[(size_t)cls * DD + i] = s;
  } else {
    int jp = j - 64;
    int cls = jp / 136, tr = jp % 136;
    int nt_, kt_; tri_decode(tr, nt_, kt_);   // nt_ >= kt_
    _Float16* outp = UT + (size_t)cls * UT_CLS_STRIDE + (size_t)tr * 4096;
    if (kt_ == nt_) {
      const float* Dv = Dinv + ((size_t)(cls * 16 + nt_)) * 4096;
      for (int idx = t; idx < 4096; idx += 256) outp[idx] = (_Float16)Dv[idx];
    } else {
      const float* Sg = sigma + ((size_t)cls << 20);
      for (int i2 = 0; i2 < 16; i2++) {
        int lin = i2 * 256 + t;
        int kp = lin >> 6, np = lin & 63;
        U0[kp * 66 + np] = Sg[(size_t)(kt_ * 64 + kp) * DD + nt_ * 64 + np];
      }
      __syncthreads();
      for (int i2 = 0; i2 < 16; i2++) {
        int lin = i2 * 256 + t;
        int np = lin >> 6, kp = lin & 63;
        outp[np * 64 + kp] = (_Float16)U0[kp * 66 + np];
      }
    }
  }
}

// ---------------- predict side ----------------
__global__ void k_xqdots(const float* Xq, const float* mu, float* xq2, float* xqmu) {
  __shared__ float xrow[DD];
  int m = blockIdx.x, t = threadIdx.x;
  for (int i = t; i < 256; i += 256)
    ((float4*)xrow)[i] = ((const float4*)(Xq + (size_t)m * DD))[i];
  __syncthreads();
  int wave = t >> 6, lane = t & 63;
  for (int cc = 0; cc < 4; cc++) {
    int c = wave * 4 + cc;
    const float* muc = mu + (size_t)c * DD;
    float s = 0.f;
    for (int j = lane; j < DD; j += 64) s += xrow[j] * muc[j];
    for (int o = 32; o > 0; o >>= 1) s += __shfl_down(s, o, 64);
    if (lane == 0) xqmu[(size_t)m * 16 + c] = s;
  }
  if (wave == 0) {
    float s = 0.f;
    for (int j = lane; j < DD; j += 64) s += xrow[j] * xrow[j];
    for (int o = 32; o > 0; o >>= 1) s += __shfl_down(s, o, 64);
    if (lane == 0) xq2[m] = s;
  }
}

// G = Xq * V^T per class from packed fp16 tiles, fused ||G-u||^2 epilogue
__global__ __launch_bounds__(256) void k_gemmG_mfma(const float* Xq, const _Float16* UT,
                                                    const float* u, float* dout) {
  int mt = blockIdx.x, ct = blockIdx.y, cls = blockIdx.z;
  const _Float16* Uc = UT + (size_t)cls * UT_CLS_STRIDE;
  __shared__ _Float16 As[128 * 40];
  __shared__ _Float16 Bs[128 * 40];
  int t = threadIdx.x;
  int wave = t >> 6, lane = t & 63;
  int wr = wave >> 1, wc = wave & 1;
  int quad = lane >> 4, l15 = lane & 15;
  int m0 = mt * 128, n0 = ct * 128, NT0 = ct * 2;
  floatx4 acc[4][4];
#pragma unroll
  for (int a = 0; a < 4; a++)
#pragma unroll
    for (int b = 0; b < 4; b++) acc[a][b] = (floatx4){0.f, 0.f, 0.f, 0.f};
  int kmax = (ct + 1) * 128;
  for (int kk = 0; kk < kmax; kk += 32) {
    __syncthreads();
#pragma unroll
    for (int i = 0; i < 4; i++) {
      int lin = i * 256 + t;
      int r = lin >> 3, c4 = (lin & 7) * 4;
      float4 v = *(const float4*)&Xq[(size_t)(m0 + r) * DD + kk + c4];
      half4 h = {(_Float16)v.x, (_Float16)v.y, (_Float16)v.z, (_Float16)v.w};
      *(half4*)&As[r * 40 + c4] = h;
    }
    int kt = kk >> 6, k0 = kk & 63;
#pragma unroll
    for (int i = 0; i < 2; i++) {
      int lin = i * 256 + t;
      int nl = lin >> 2, kg = (lin & 3) * 8;
      int s = nl >> 6, np = nl & 63;
      int nt = NT0 + s;
      half8 v = {};
      if (kt <= nt)
        v = *(const half8*)&Uc[(size_t)(nt * (nt + 1) / 2 + kt) * 4096 + np * 64 + k0 + kg];
      *(half8*)&Bs[nl * 40 + kg] = v;
    }
    __syncthreads();
    half8 af[4], bf[4];
#pragma unroll
    for (int f = 0; f < 4; f++) {
      af[f] = *(const half8*)&As[(wr * 64 + f * 16 + l15) * 40 + quad * 8];
      bf[f] = *(const half8*)&Bs[(wc * 64 + f * 16 + l15) * 40 + quad * 8];
    }
#pragma unroll
    for (int fi = 0; fi < 4; fi++)
#pragma unroll
      for (int fj = 0; fj < 4; fj++)
        acc[fi][fj] = __builtin_amdgcn_mfma_f32_16x16x32_f16(af[fi], bf[fj], acc[fi][fj], 0, 0, 0);
  }
  float uv[4];
#pragma unroll
  for (int fj = 0; fj < 4; fj++)
    uv[fj] = u[(size_t)cls * DD + n0 + wc * 64 + fj * 16 + l15];
#pragma unroll
  for (int fi = 0; fi < 4; fi++) {
#pragma unroll
    for (int r = 0; r < 4; r++) {
      float p = 0.f;
#pragma unroll
      for (int fj = 0; fj < 4; fj++) {
        float e = acc[fi][fj][r] - uv[fj];
        p += e * e;
      }
      p += __shfl_xor(p, 1, 64);
      p += __shfl_xor(p, 2, 64);
      p += __shfl_xor(p, 4, 64);
      p += __shfl_xor(p, 8, 64);
      if (l15 == 0) {
        int m = m0 + wr * 64 + fi * 16 + quad * 4 + r;
        atomicAdd(&dout[(size_t)m * 16 + cls], p);
      }
    }
  }
}

__global__ void k_logits(const float* xq2, const float* xqmu, const float* mu2,
                         float* dout) {
  size_t idx = (size_t)blockIdx.x * 256 + threadIdx.x;
  int m = (int)(idx >> 4), c = (int)(idx & 15);
  float q1 = dout[idx];
  float q2 = xq2[m] - 2.0f * xqmu[idx] + mu2[c];
  dout[idx] = -(0.9f * q1 + 0.1f * q2);
}

extern "C" void kernel_launch(void* const* d_in, const int* in_sizes, int n_in,
                              void* d_out, int out_size, void* d_ws, size_t ws_size,
                              hipStream_t stream) {
  (void)in_sizes; (void)n_in; (void)out_size; (void)ws_size;
  const float* X  = (const float*)d_in[0];
  const int*   y  = (const int*)d_in[1];
  const float* Xq = (const float*)d_in[2];
  const float* m  = (const float*)d_in[3];
  const float* kappa = (const float*)d_in[4];
  const float* nu = (const float*)d_in[5];
  const float* td = (const float*)d_in[6];
  const float* tl = (const float*)d_in[7];
  float* out = (float*)d_out;
  float* ws = (float*)d_ws;

  short* XTh   = (short*)(ws + OFF_XTH);
  short* XTl   = (short*)(ws + OFF_XTL);
  _Float16* UT = (_Float16*)ws;              // overlays XT planes (dead after syrk)
  float* baseb = ws + OFF_BASE;
  float* sigma = ws + OFF_SIGMA;
  float* Lm    = sigma;                      // L overlays sigma (dead before syrk writes)
  float* Dinv  = ws + OFF_DINV;
  float* sums  = ws + OFF_SUMS;
  float* mu    = ws + OFF_MU;
  float* uarr  = ws + OFF_U;
  float* mu2   = ws + OFF_MU2;
  float* xq2   = ws + OFF_XQ2;
  float* xqmu  = ws + OFF_XQMU;
  float* kapnu = ws + OFF_KAPNU;
  float* cf    = ws + OFF_CF;
  float* beta  = ws + OFF_BETA;
  float* invs  = ws + OFF_INVS;
  int* ints    = (int*)(ws + OFF_INTS);
  int* counts  = ints;
  int* offsets = ints + 16;
  int* cursor  = ints + 32;
  int* order   = ints + 48;

  hipMemsetAsync(XTh, 0, (size_t)18874368, stream);   // both bf16 planes
  hipMemsetAsync(out, 0, (size_t)4096 * 16 * 4, stream);

  k_scalars<<<1, 256, 0, stream>>>(y, kappa, nu, kapnu, cf, beta, invs,
                                   counts, offsets, cursor, order, sums);
  k_colsums<<<dim3(4, 32), 256, 0, stream>>>(X, y, sums);
  k_mu<<<64, 256, 0, stream>>>(sums, m, kapnu, cf, mu);
  k_mu2<<<16, 256, 0, stream>>>(mu, mu2);
  k_scatter<<<16, 256, 0, stream>>>(y, cursor, order);
  k_gatherT<<<dim3(72, 16), 256, 0, stream>>>(X, order, XTh, XTl);
  k_buildL<<<4096, 256, 0, stream>>>(td, tl, Lm);
  k_base<<<136, 256, 0, stream>>>(Lm, m, kapnu, baseb);
  k_syrk_mfma<<<16 * 36, 256, 0, stream>>>(XTh, XTl, baseb, mu, beta, invs,
                                           counts, offsets, sigma);
  k_diag0<<<16, 256, 0, stream>>>(sigma, Dinv);
  for (int k = 0; k < 15; k++) {
    int nb = 15 - k;
    k_panel<<<16 * nb, 256, 0, stream>>>(sigma, Dinv, k);
    int nt = nb * (nb + 1) / 2;
    k_syrkdiag<<<16 * nt, 256, 0, stream>>>(sigma, Dinv, k);
  }
  for (int l = 1; l <= 15; l++)
    k_vlevel<<<16 * (16 - l), 256, 0, stream>>>(sigma, Dinv, l);
  k_finalize<<<64 + 16 * 136, 256, 0, stream>>>(sigma, Dinv, mu, uarr, UT);
  k_xqdots<<<4096, 256, 0, stream>>>(Xq, mu, xq2, xqmu);
  k_gemmG_mfma<<<dim3(32, 8, 16), 256, 0, stream>>>(Xq, UT, uarr, out);
  k_logits<<<256, 256, 0, stream>>>(xq2, xqmu, mu2, out);
}